// Round 1
// baseline (2683.924 us; speedup 1.0000x reference)
//
#include <hip/hip_runtime.h>
#include <hip/hip_bf16.h>

// EqProp free phase. Layers: s0[B,10], s1[B,512], s2[B,512], x[B,784] clamped.
// State packed as [B, 1034]: cols [0,10)=s0, [10,522)=s1, [522,1034)=s2.
// Invariant: states stay in [0,1] => rho(s)=s, rhop(s)=1.
// Step: n_i = clip(0.5*s_i + 0.5*z_i), with
//   z0 = s1 @ W0^T + b0
//   z1 = s2 @ W1^T + b1 + s0 @ W0
//   z2 = (rho(x) @ W2^T + b2) [precomputed c2] + s1 @ W1

#define BATCH 4096
#define CSTRIDE 1034
#define OFF1 10
#define OFF2 522

// ---------------- init: pack s0,s1,s2 into state buffer A ----------------
__global__ void k_init(float* __restrict__ A, const float* __restrict__ s0,
                       const float* __restrict__ s1, const float* __restrict__ s2) {
    const size_t total = (size_t)BATCH * CSTRIDE;
    for (size_t i = (size_t)blockIdx.x * blockDim.x + threadIdx.x; i < total;
         i += (size_t)gridDim.x * blockDim.x) {
        int b = (int)(i / CSTRIDE);
        int c = (int)(i % CSTRIDE);
        float v;
        if (c < OFF1)      v = s0[(size_t)b * 10 + c];
        else if (c < OFF2) v = s1[(size_t)b * 512 + (c - OFF1)];
        else               v = s2[(size_t)b * 512 + (c - OFF2)];
        A[i] = v;
    }
}

// ---------------- c2 = rho(x) @ W2^T + b2  (B x 512, K=784) ----------------
__global__ __launch_bounds__(256) void k_c2(const float* __restrict__ x,
                                            const float* __restrict__ W2,
                                            const float* __restrict__ b2,
                                            float* __restrict__ c2) {
    __shared__ float As[16][68];
    __shared__ float Bs[16][68];
    const int bm = blockIdx.x * 64, bn = blockIdx.y * 64;
    const int tid = threadIdx.x, tx = tid & 15, ty = tid >> 4;
    float acc[4][4] = {};
    for (int k0 = 0; k0 < 784; k0 += 16) {
        const int r = tid >> 4, c = tid & 15;
#pragma unroll
        for (int q = 0; q < 4; ++q) {
            float v = x[(size_t)(bm + r + 16 * q) * 784 + k0 + c];
            As[c][r + 16 * q] = fminf(fmaxf(v, 0.f), 1.f);   // rho(x)
        }
#pragma unroll
        for (int q = 0; q < 4; ++q)
            Bs[c][r + 16 * q] = W2[(size_t)(bn + r + 16 * q) * 784 + k0 + c];
        __syncthreads();
#pragma unroll
        for (int k = 0; k < 16; ++k) {
            float a[4], b[4];
#pragma unroll
            for (int i = 0; i < 4; ++i) a[i] = As[k][ty * 4 + i];
#pragma unroll
            for (int j = 0; j < 4; ++j) b[j] = Bs[k][tx * 4 + j];
#pragma unroll
            for (int i = 0; i < 4; ++i)
#pragma unroll
                for (int j = 0; j < 4; ++j) acc[i][j] += a[i] * b[j];
        }
        __syncthreads();
    }
#pragma unroll
    for (int i = 0; i < 4; ++i) {
        int gb = bm + ty * 4 + i;
#pragma unroll
        for (int j = 0; j < 4; ++j) {
            int cl = tx * 4 + j;
            c2[(size_t)gb * 512 + bn + cl] = acc[i][j] + b2[bn + cl];
        }
    }
}

// ---------------- z1: new_s1 = clip(0.5*s1 + 0.5*(s2@W1^T + b1 + s0@W0)) ----------------
__global__ __launch_bounds__(256) void k_z1(const float* __restrict__ oldS,
                                            float* __restrict__ nw,
                                            const float* __restrict__ W1,
                                            const float* __restrict__ b1,
                                            const float* __restrict__ W0) {
    __shared__ float As[16][68];
    __shared__ float Bs[16][68];
    __shared__ float S0s[64][12];
    __shared__ float W0s[10][68];
    const int bm = blockIdx.x * 64, bn = blockIdx.y * 64;
    const int tid = threadIdx.x, tx = tid & 15, ty = tid >> 4;
    float acc[4][4] = {};
    for (int i = tid; i < 64 * 10; i += 256) {
        int r = i / 10, c = i % 10;
        S0s[r][c] = oldS[(size_t)(bm + r) * CSTRIDE + c];
    }
    for (int i = tid; i < 64 * 10; i += 256) {
        int r = i / 64, c = i % 64;
        W0s[r][c] = W0[(size_t)r * 512 + bn + c];
    }
    for (int k0 = 0; k0 < 512; k0 += 16) {
        const int r = tid >> 4, c = tid & 15;
#pragma unroll
        for (int q = 0; q < 4; ++q)
            As[c][r + 16 * q] = oldS[(size_t)(bm + r + 16 * q) * CSTRIDE + OFF2 + k0 + c];
#pragma unroll
        for (int q = 0; q < 4; ++q)
            Bs[c][r + 16 * q] = W1[(size_t)(bn + r + 16 * q) * 512 + k0 + c];
        __syncthreads();
#pragma unroll
        for (int k = 0; k < 16; ++k) {
            float a[4], b[4];
#pragma unroll
            for (int i = 0; i < 4; ++i) a[i] = As[k][ty * 4 + i];
#pragma unroll
            for (int j = 0; j < 4; ++j) b[j] = Bs[k][tx * 4 + j];
#pragma unroll
            for (int i = 0; i < 4; ++i)
#pragma unroll
                for (int j = 0; j < 4; ++j) acc[i][j] += a[i] * b[j];
        }
        __syncthreads();
    }
#pragma unroll
    for (int i = 0; i < 4; ++i) {
        int r = ty * 4 + i, gb = bm + r;
#pragma unroll
        for (int j = 0; j < 4; ++j) {
            int cl = tx * 4 + j;
            float z = acc[i][j] + b1[bn + cl];
#pragma unroll
            for (int k = 0; k < 10; ++k) z += S0s[r][k] * W0s[k][cl];
            size_t o = (size_t)gb * CSTRIDE + OFF1 + bn + cl;
            float v = 0.5f * oldS[o] + 0.5f * z;
            nw[o] = fminf(fmaxf(v, 0.f), 1.f);
        }
    }
}

// ---------------- z2: new_s2 = clip(0.5*s2 + 0.5*(c2 + s1@W1)) ----------------
__global__ __launch_bounds__(256) void k_z2(const float* __restrict__ oldS,
                                            float* __restrict__ nw,
                                            const float* __restrict__ W1,
                                            const float* __restrict__ c2) {
    __shared__ float As[16][68];
    __shared__ float Bs[16][68];
    const int bm = blockIdx.x * 64, bn = blockIdx.y * 64;
    const int tid = threadIdx.x, tx = tid & 15, ty = tid >> 4;
    float acc[4][4] = {};
    for (int k0 = 0; k0 < 512; k0 += 16) {
        {
            const int r = tid >> 4, c = tid & 15;
#pragma unroll
            for (int q = 0; q < 4; ++q)
                As[c][r + 16 * q] = oldS[(size_t)(bm + r + 16 * q) * CSTRIDE + OFF1 + k0 + c];
        }
        {
            const int j = tid & 63, kk = tid >> 6;
#pragma unroll
            for (int q = 0; q < 4; ++q)
                Bs[kk + 4 * q][j] = W1[(size_t)(k0 + kk + 4 * q) * 512 + bn + j];
        }
        __syncthreads();
#pragma unroll
        for (int k = 0; k < 16; ++k) {
            float a[4], b[4];
#pragma unroll
            for (int i = 0; i < 4; ++i) a[i] = As[k][ty * 4 + i];
#pragma unroll
            for (int j = 0; j < 4; ++j) b[j] = Bs[k][tx * 4 + j];
#pragma unroll
            for (int i = 0; i < 4; ++i)
#pragma unroll
                for (int j = 0; j < 4; ++j) acc[i][j] += a[i] * b[j];
        }
        __syncthreads();
    }
#pragma unroll
    for (int i = 0; i < 4; ++i) {
        int gb = bm + ty * 4 + i;
#pragma unroll
        for (int j = 0; j < 4; ++j) {
            int cl = tx * 4 + j;
            float z = acc[i][j] + c2[(size_t)gb * 512 + bn + cl];
            size_t o = (size_t)gb * CSTRIDE + OFF2 + bn + cl;
            float v = 0.5f * oldS[o] + 0.5f * z;
            nw[o] = fminf(fmaxf(v, 0.f), 1.f);
        }
    }
}

// ---------------- z0: new_s0 = clip(0.5*s0 + 0.5*(s1@W0^T + b0)) ----------------
__global__ __launch_bounds__(256) void k_z0(const float* __restrict__ oldS,
                                            float* __restrict__ nw,
                                            const float* __restrict__ W0,
                                            const float* __restrict__ b0) {
    __shared__ float W0s[10 * 512];
    for (int i = threadIdx.x; i < 5120; i += 256) W0s[i] = W0[i];
    __syncthreads();
    const int row = threadIdx.x >> 4;   // 16 rows per block
    const int kq = threadIdx.x & 15;
    const int gb = blockIdx.x * 16 + row;
    const float* srow = oldS + (size_t)gb * CSTRIDE + OFF1;
    float acc[10];
#pragma unroll
    for (int j = 0; j < 10; ++j) acc[j] = 0.f;
    for (int k = kq; k < 512; k += 16) {
        float a = srow[k];
#pragma unroll
        for (int j = 0; j < 10; ++j) acc[j] += a * W0s[j * 512 + k];
    }
#pragma unroll
    for (int j = 0; j < 10; ++j) {
#pragma unroll
        for (int off = 1; off < 16; off <<= 1)
            acc[j] += __shfl_xor(acc[j], off);
    }
    if (kq == 0) {
#pragma unroll
        for (int j = 0; j < 10; ++j) {
            size_t o = (size_t)gb * CSTRIDE + j;
            float v = 0.5f * oldS[o] + 0.5f * (acc[j] + b0[j]);
            nw[o] = fminf(fmaxf(v, 0.f), 1.f);
        }
    }
}

extern "C" void kernel_launch(void* const* d_in, const int* in_sizes, int n_in,
                              void* d_out, int out_size, void* d_ws, size_t ws_size,
                              hipStream_t stream) {
    const float* s0 = (const float*)d_in[0];
    const float* s1 = (const float*)d_in[1];
    const float* s2 = (const float*)d_in[2];
    const float* x  = (const float*)d_in[3];
    const float* W0 = (const float*)d_in[4];
    const float* b0 = (const float*)d_in[5];
    const float* W1 = (const float*)d_in[6];
    const float* b1 = (const float*)d_in[7];
    const float* W2 = (const float*)d_in[8];
    const float* b2 = (const float*)d_in[9];

    float* A    = (float*)d_out;                       // ping buffer (final state lands here)
    float* Bbuf = (float*)d_ws;                        // pong buffer
    float* c2   = Bbuf + (size_t)BATCH * CSTRIDE;      // precomputed rho(x)@W2^T + b2

    k_init<<<4096, 256, 0, stream>>>(A, s0, s1, s2);
    k_c2<<<dim3(64, 8), 256, 0, stream>>>(x, W2, b2, c2);

    for (int t = 0; t < 30; ++t) {
        const float* src = (t & 1) ? Bbuf : A;
        float* dst       = (t & 1) ? A : Bbuf;
        k_z0<<<256, 256, 0, stream>>>(src, dst, W0, b0);
        k_z1<<<dim3(64, 8), 256, 0, stream>>>(src, dst, W1, b1, W0);
        k_z2<<<dim3(64, 8), 256, 0, stream>>>(src, dst, W1, c2);
    }
    // t=29 (odd) wrote into A == d_out: output is [s0|s1|s2] packed, done.
}